// Round 8
// baseline (145.083 us; speedup 1.0000x reference)
//
#include <hip/hip_runtime.h>

#define BB 16
#define PP 131072
#define GG 64
#define THRESH 0.35f
#define RMAX 0.086f          // max prior half-extent 0.085 + slop margin
#define NCHUNK 16            // blocks per image
#define CPRIOR 8192          // priors per chunk

// ---------------- workspace layout (bytes) ----------------
#define OFF_BESTP   0          // u64[BB][16][64]    131072
#define OFF_H1C     131072     // u32[BB][16][4096]  4194304
#define OFF_H1S     4325376    // f32[BB][16][4096]  4194304
#define OFF_H1TOT   8519680    // u32[BB][4096]      262144
#define OFF_H1STOT  8781824    // f32[BB][4096]      262144
#define OFF_NPOSP   9043968    // i32[BB][16]        1024
#define OFF_PCP     9044992    // f32[BB][16]        1024
#define OFF_LOCP    9046016    // f32[BB][16]        1024
#define OFF_CIDX    9047040    // u32[BB]            64
#define OFF_DONE    9047104    // u32                64
#define OFF_BAR     9047168    // u32[BB][4]         256
#define OFF_RESN    9047424    // i32[BB]
#define OFF_RESK    9047488    // i32[BB]
#define OFF_RESC    9047552    // f32[BB]
#define OFF_RESL    9047616    // f32[BB]
#define OFF_CAND    9047680    // u32[BB*PP]  8388608   (total ~17.4 MB)

// ---------------- init: zero sync state (poison-proof) ----------------
__global__ void k_init(unsigned* __restrict__ cidx, unsigned* __restrict__ done,
                       unsigned* __restrict__ bar)
{
    const int t = threadIdx.x;
    if (t < BB) cidx[t] = 0u;
    if (t == BB) *done = 0u;
    if (t >= 32 && t < 32 + BB * 4) bar[t - 32] = 0u;
}

// per-image barrier: 16 blocks arrive on one device-scope counter.
__device__ __forceinline__ void image_barrier(unsigned* ctr)
{
    __syncthreads();
    if (threadIdx.x == 0) {
        __threadfence();                               // release our writes
        atomicAdd(ctr, 1u);
        while (atomicAdd(ctr, 0u) < NCHUNK)            // device-scope read
            __builtin_amdgcn_s_sleep(16);
        __threadfence();                               // acquire others' writes
    }
    __syncthreads();
}

// ---------------- parallel descending k-th finder (1024-thread block) ----------------
template <int NBINS>
__device__ void find_kth_par(const unsigned* __restrict__ h, int k, int* sel, int* krem)
{
    constexpr int PER = NBINS / 1024;
    __shared__ unsigned wsum_[16];
    __shared__ int res_[2];
    const int tid = threadIdx.x, lane = tid & 63, wid = tid >> 6;
    __syncthreads();
    unsigned own[PER];
    unsigned s = 0;
#pragma unroll
    for (int i = 0; i < PER; i++) { own[i] = h[NBINS - 1 - (tid * PER + i)]; s += own[i]; }
    unsigned incl = s;
    for (int d = 1; d < 64; d <<= 1) {
        unsigned t = __shfl_up(incl, d);
        if (lane >= d) incl += t;
    }
    if (lane == 63) wsum_[wid] = incl;
    if (tid == 0) { res_[0] = -1; res_[1] = 0; }
    __syncthreads();
    unsigned woff = 0;
    for (int w = 0; w < 16; w++) woff += (w < wid) ? wsum_[w] : 0u;
    const unsigned texcl = woff + incl - s;
    if (k > 0 && texcl < (unsigned)k && texcl + s >= (unsigned)k) {
        unsigned run = texcl;
#pragma unroll
        for (int i = 0; i < PER; i++) {
            run += own[i];
            if (run >= (unsigned)k) {
                res_[0] = NBINS - 1 - (tid * PER + i);
                res_[1] = k - (int)(run - own[i]);
                break;
            }
        }
    }
    __syncthreads();
    *sel = res_[0]; *krem = res_[1];
}

__device__ float block_sum_f(float v)
{
    __shared__ float rs[16];
    const int tid = threadIdx.x;
    __syncthreads();
    for (int o = 32; o; o >>= 1) v += __shfl_xor(v, o);
    if ((tid & 63) == 0) rs[tid >> 6] = v;
    __syncthreads();
    float s = 0.f;
    for (int i = 0; i < 16; i++) s += rs[i];
    return s;
}

// ---------------- the fused kernel ----------------
// grid (NCHUNK, BB) x 1024. Phases: match -> loss/hist -> h1 reduce ->
// sel1+compact -> select+final. bv/bg/kv stay in REGISTERS across phases
// (same block owns the same 8192 priors throughout) — bto/bti/keys arrays
// and their ~26 MB of traffic are gone.
__global__ __launch_bounds__(1024) void k_all(
    const float* __restrict__ loc_preds, const float* __restrict__ cls_preds,
    const float* __restrict__ priorbox, const float* __restrict__ targets,
    unsigned long long* __restrict__ bestp,
    unsigned* __restrict__ h1c, float* __restrict__ h1s,
    unsigned* __restrict__ h1tot, float* __restrict__ h1stot,
    int* __restrict__ nposp, float* __restrict__ pcp, float* __restrict__ locp,
    unsigned* __restrict__ cidx, unsigned* __restrict__ done, unsigned* __restrict__ bar,
    int* __restrict__ resn, int* __restrict__ resk,
    float* __restrict__ resc, float* __restrict__ resl,
    unsigned* __restrict__ cand, float* __restrict__ out)
{
    __shared__ float4 gxy[GG];
    __shared__ float gar[GG];
    __shared__ float glab[GG];
    __shared__ unsigned long long sbest[GG];
    __shared__ unsigned blist[GG];
    __shared__ int nb;
    __shared__ float sred[32];
    __shared__ int sredi[16];
    __shared__ unsigned wcnt[16], wbase[16];
    __shared__ unsigned bbase;
    __shared__ int lastflag;
    __shared__ union SM {
        struct { unsigned mlo[4096], mhi[4096]; } p1;
        struct { unsigned long long tmp64[1024]; } p2a;
        struct { unsigned hcnt[4096]; float hsum[4096]; } p2b;
        struct { unsigned ch[1024]; float cs[1024]; } p4;
    } U;

    const int b = blockIdx.y, chunk = blockIdx.x, tid = threadIdx.x;
    const int lane = tid & 63, wid = tid >> 6;

    // ================= P1: raster mask + match (registers out) =================
    for (int i = tid; i < 4096; i += 1024) { U.p1.mlo[i] = 0u; U.p1.mhi[i] = 0u; }
    if (tid < GG) {
        const float* t = targets + (size_t)(b * GG + tid) * 5;
        float x1 = t[1], y1 = t[0], x2 = t[3], y2 = t[2];   // gts = t[[1,0,3,2]]
        gxy[tid] = make_float4(x1, y1, x2, y2);
        gar[tid] = (x2 - x1) * (y2 - y1);
        glab[tid] = t[4];
        sbest[tid] = 0ull;
    }
    __syncthreads();
    {
        const int g = tid & 63, strip = tid >> 6;
        float4 a = gxy[g];
        float ex1 = a.x - RMAX, ey1 = a.y - RMAX;
        float ex2 = a.z + RMAX, ey2 = a.w + RMAX;
        int cx0 = max(0, (int)(ex1 * 64.f));
        int cx1 = min(63, (int)ceilf(ex2 * 64.f) - 1);
        int cy0 = max(0, (int)(ey1 * 64.f));
        int cy1 = min(63, (int)ceilf(ey2 * 64.f) - 1);
        unsigned bit = 1u << (g & 31);
        unsigned* marr = (g < 32) ? U.p1.mlo : U.p1.mhi;
        for (int cy = cy0 + strip; cy <= cy1; cy += 16)
            for (int cx = cx0; cx <= cx1; cx++)
                atomicOr(&marr[cy * 64 + cx], bit);
    }
    __syncthreads();

    float bv[8]; int bg[8];
#pragma unroll
    for (int j = 0; j < 8; j++) {
        const int p = chunk * CPRIOR + j * 1024 + tid;
        float4 pr = *reinterpret_cast<const float4*>(priorbox + (size_t)p * 4);
        float hx = 0.5f * pr.z, hy = 0.5f * pr.w;
        float px1 = pr.x - hx, py1 = pr.y - hy;
        float px2 = pr.x + hx, py2 = pr.y + hy;
        float par = (px2 - px1) * (py2 - py1);
        int cx = min(63, max(0, (int)(pr.x * 64.f)));
        int cy = min(63, max(0, (int)(pr.y * 64.f)));
        const int cell = cy * 64 + cx;
        unsigned m0 = U.p1.mlo[cell], m1 = U.p1.mhi[cell];
        const unsigned long long notp = (unsigned long long)(~(unsigned)p);
        float bvj = -1.f; int bgj = 0;
#pragma unroll 1
        for (int half = 0; half < 2; half++) {
            unsigned m = half ? m1 : m0;
            const int gbase = half ? 32 : 0;
            while (m) {
                const int g = gbase + __ffs(m) - 1;       // ascending g: first-max tiebreak
                m &= m - 1;
                float4 a = gxy[g];
                float w = fminf(a.z, px2) - fmaxf(a.x, px1);
                float h = fminf(a.w, py2) - fmaxf(a.y, py1);
                w = fmaxf(w, 0.f); h = fmaxf(h, 0.f);
                float inter = w * h;
                float v = inter * __builtin_amdgcn_rcpf(gar[g] + par - inter);
                if (v > bvj) { bvj = v; bgj = g; }
                if (v > 0.f) {
                    unsigned long long pk =
                        (((unsigned long long)__float_as_uint(v)) << 32) | notp;
                    atomicMax(&sbest[g], pk);
                }
            }
        }
        bv[j] = bvj; bg[j] = bgj;
    }
    __syncthreads();
    if (tid < GG) bestp[(b * NCHUNK + chunk) * GG + tid] = sbest[tid];

    image_barrier(bar + b * 4 + 0);

    // ================= P2: decode blist + loss + hist partials =================
    U.p2a.tmp64[tid] = bestp[(b * NCHUNK + (tid >> 6)) * GG + (tid & 63)];
    __syncthreads();
    if (tid < GG) {
        unsigned long long m = U.p2a.tmp64[tid];
        for (int c = 1; c < NCHUNK; c++) {
            unsigned long long v = U.p2a.tmp64[c * GG + tid];
            m = v > m ? v : m;
        }
        U.p2a.tmp64[tid] = m;
    }
    __syncthreads();
    if (tid == 0) {
        int n = 0;
        for (int g = 0; g < GG; g++) {                    // ascending g: later-g wins at dup p
            unsigned long long m = U.p2a.tmp64[g];
            if (m) {
                unsigned p = ~((unsigned)(m & 0xFFFFFFFFull));
                if ((int)(p >> 13) == chunk) blist[n++] = ((p & 8191u) << 6) | (unsigned)g;
            }
        }
        nb = n;
    }
    __syncthreads();
    const int nbl = nb;
    for (int i = tid; i < 4096; i += 1024) { U.p2b.hcnt[i] = 0u; U.p2b.hsum[i] = 0.f; }
    __syncthreads();

    unsigned kv[8];
    float locpart = 0.f, clspart = 0.f; int cnt = 0;
#pragma unroll
    for (int j = 0; j < 8; j++) {
        const int plocal = j * 1024 + tid;
        const size_t ip = (size_t)b * PP + chunk * CPRIOR + plocal;
        int g = bg[j];
        bool isb = false;
        for (int i = 0; i < nbl; i++) {
            unsigned e = blist[i];
            if ((int)(e >> 6) == plocal) { isb = true; g = (int)(e & 63u); }
        }
        const float2 cl = *reinterpret_cast<const float2*>(cls_preds + ip * 2);
        const float mx = fmaxf(cl.x, cl.y);
        const float lse = mx + log1pf(expf(fminf(cl.x, cl.y) - mx));
        const float conf = isb ? glab[g] : ((bv[j] < THRESH) ? 0.f : glab[g]);
        unsigned key = 0u;
        if (conf > 0.f) {
            float gathered = (((int)conf) == 0) ? cl.x : cl.y;
            clspart += lse - gathered;
            cnt++;
            const int p = chunk * CPRIOR + plocal;
            float4 pr = *reinterpret_cast<const float4*>(priorbox + (size_t)p * 4);
            float4 gt = gxy[g];
            float gcx = ((gt.x + gt.z) * 0.5f - pr.x) / (0.1f * pr.z);
            float gcy = ((gt.y + gt.w) * 0.5f - pr.y) / (0.1f * pr.w);
            float gw = logf((gt.z - gt.x) / pr.z) / 0.2f;
            float gh = logf((gt.w - gt.y) / pr.w) / 0.2f;
            float4 lp = *reinterpret_cast<const float4*>(loc_preds + ip * 4);
            float d0 = lp.x - gcx, d1 = lp.y - gcy, d2 = lp.z - gw, d3 = lp.w - gh;
            float a0 = fabsf(d0), a1 = fabsf(d1), a2 = fabsf(d2), a3 = fabsf(d3);
            locpart += ((a0 < 1.f) ? 0.5f * d0 * d0 : a0 - 0.5f)
                     + ((a1 < 1.f) ? 0.5f * d1 * d1 : a1 - 0.5f)
                     + ((a2 < 1.f) ? 0.5f * d2 * d2 : a2 - 0.5f)
                     + ((a3 < 1.f) ? 0.5f * d3 * d3 : a3 - 0.5f);
        } else {
            float lc = lse - cl.x;                         // > 0 strictly for negs
            key = __float_as_uint(lc);
            atomicAdd(&U.p2b.hcnt[key >> 20], 1u);
            atomicAdd(&U.p2b.hsum[key >> 20], lc);
        }
        kv[j] = key;
    }

    for (int o = 32; o; o >>= 1) {
        locpart += __shfl_xor(locpart, o);
        clspart += __shfl_xor(clspart, o);
        cnt     += __shfl_xor(cnt, o);
    }
    if (lane == 0) { sred[wid] = locpart; sred[16 + wid] = clspart; sredi[wid] = cnt; }
    __syncthreads();
    if (tid == 0) {
        float l = 0.f, c = 0.f; int n = 0;
        for (int i = 0; i < 16; i++) { l += sred[i]; c += sred[16 + i]; n += sredi[i]; }
        nposp[b * NCHUNK + chunk] = n;
        pcp[b * NCHUNK + chunk] = c;
        locp[b * NCHUNK + chunk] = l;
    }
    __syncthreads();
    for (int i = tid; i < 4096; i += 1024) {
        h1c[(b * NCHUNK + chunk) * 4096 + i] = U.p2b.hcnt[i];
        h1s[(b * NCHUNK + chunk) * 4096 + i] = U.p2b.hsum[i];
    }

    image_barrier(bar + b * 4 + 1);

    // ================= P3a: reduce h1 partials (each block: its 256-bin slice) =====
    if (tid < 256) {
        const int i = chunk * 256 + tid;
        unsigned s = 0;
        for (int cc = 0; cc < NCHUNK; cc++) s += h1c[(b * NCHUNK + cc) * 4096 + i];
        h1tot[b * 4096 + i] = s;
    } else if (tid < 512) {
        const int i = chunk * 256 + (tid - 256);
        float s = 0.f;
        for (int cc = 0; cc < NCHUNK; cc++) s += h1s[(b * NCHUNK + cc) * 4096 + i];
        h1stot[b * 4096 + i] = s;
    }

    image_barrier(bar + b * 4 + 2);

    // ================= P3b: sel1 (redundant) + register compaction =================
    int np = 0;
    for (int c = 0; c < NCHUNK; c++) np += nposp[b * NCHUNK + c];
    const int k = min(3 * np, PP - 1);
    int sel1, kk1;
    find_kth_par<4096>(h1tot + b * 4096, k, &sel1, &kk1);
    const unsigned s1 = (unsigned)sel1;                   // -1 matches nothing

    unsigned long long mv[8];
    unsigned wn = 0;
#pragma unroll
    for (int j = 0; j < 8; j++) {
        mv[j] = __ballot((kv[j] >> 20) == s1);
        wn += (unsigned)__popcll(mv[j]);
    }
    if (lane == 0) wcnt[wid] = wn;
    __syncthreads();
    if (tid == 0) {
        unsigned run = 0;
        for (int w = 0; w < 16; w++) { wbase[w] = run; run += wcnt[w]; }
        bbase = run ? atomicAdd(&cidx[b], run) : 0u;      // 1 returning atomic / block
    }
    __syncthreads();
    {
        unsigned run = bbase + wbase[wid];
        const unsigned long long lanemask = (1ull << lane) - 1ull;
#pragma unroll
        for (int j = 0; j < 8; j++) {
            if ((kv[j] >> 20) == s1)
                cand[(size_t)b * PP + run + (unsigned)__popcll(mv[j] & lanemask)] = kv[j];
            run += (unsigned)__popcll(mv[j]);
        }
    }

    image_barrier(bar + b * 4 + 3);

    // ================= P4: select (chunk-0 blocks) + cross-image final ============
    if (chunk != 0) return;

    const unsigned ncand = cidx[b];
    float nh = 0.f;
    for (int i = tid; i < 4096; i += 1024)
        if (i > sel1) nh += h1stot[b * 4096 + i];
    float negsum_high = block_sum_f(nh);

    __syncthreads();
    U.p4.ch[tid] = 0u; U.p4.cs[tid] = 0.f;
    __syncthreads();
    for (unsigned i = tid; i < ncand; i += 1024) {
        unsigned v = cand[(size_t)b * PP + i];
        unsigned bin = (v >> 10) & 1023u;
        atomicAdd(&U.p4.ch[bin], 1u);
        atomicAdd(&U.p4.cs[bin], __uint_as_float(v));
    }
    __syncthreads();
    int sel2, kk2;
    find_kth_par<1024>(U.p4.ch, (sel1 < 0) ? 0 : kk1, &sel2, &kk2);
    float sumhi2 = block_sum_f((sel2 >= 0 && tid > sel2) ? U.p4.cs[tid] : 0.f);

    __syncthreads();
    U.p4.ch[tid] = 0u; U.p4.cs[tid] = 0.f;
    __syncthreads();
    if (sel2 >= 0) {
        for (unsigned i = tid; i < ncand; i += 1024) {
            unsigned v = cand[(size_t)b * PP + i];
            if (((v >> 10) & 1023u) == (unsigned)sel2) {
                atomicAdd(&U.p4.ch[v & 1023u], 1u);
                atomicAdd(&U.p4.cs[v & 1023u], __uint_as_float(v));
            }
        }
    }
    __syncthreads();
    int sel3, needeq;
    find_kth_par<1024>(U.p4.ch, (sel2 < 0) ? 0 : kk2, &sel3, &needeq);
    float sumhi3 = block_sum_f((sel3 >= 0 && tid > sel3) ? U.p4.cs[tid] : 0.f);

    if (tid == 0) {
        float pcsum = 0.f, locsum = 0.f;
        for (int c = 0; c < NCHUNK; c++) {
            pcsum += pcp[b * NCHUNK + c];
            locsum += locp[b * NCHUNK + c];
        }
        float add = 0.f;
        if (sel3 >= 0 && needeq > 0) {
            unsigned Kstar = ((unsigned)sel1 << 20) | ((unsigned)sel2 << 10) | (unsigned)sel3;
            add = needeq * __uint_as_float(Kstar);
        }
        resn[b] = np;
        resk[b] = k;
        resc[b] = pcsum + negsum_high + sumhi2 + sumhi3 + add;
        resl[b] = locsum;
        __threadfence();
        unsigned old = atomicAdd(done, 1u);
        lastflag = (old == BB - 1) ? 1 : 0;
    }
    __syncthreads();
    if (!lastflag || tid != 0) return;

    __threadfence();
    volatile int* vrn = (volatile int*)resn;
    volatile int* vrk = (volatile int*)resk;
    volatile float* vrc = (volatile float*)resc;
    volatile float* vrl = (volatile float*)resl;
    int npt = 0; long long maskc = 0; float clsnum = 0.f, locnum = 0.f;
    for (int b2 = 0; b2 < BB; b2++) {
        npt += vrn[b2];
        maskc += (long long)vrn[b2] + vrk[b2];
        clsnum += vrc[b2];
        locnum += vrl[b2];
    }
    float denom_loc = (float)((4 * npt > 1) ? 4 * npt : 1);
    float denom_cls = (float)((maskc > 1) ? maskc : 1);
    float loss_loc = locnum / denom_loc;
    float loss_cls = clsnum / denom_cls;
    out[0] = (loss_cls + loss_loc) / (float)npt;
    out[1] = loss_loc;
    out[2] = loss_cls;
}

extern "C" void kernel_launch(void* const* d_in, const int* in_sizes, int n_in,
                              void* d_out, int out_size, void* d_ws, size_t ws_size,
                              hipStream_t stream)
{
    const float* loc_preds = (const float*)d_in[0];
    const float* cls_preds = (const float*)d_in[1];
    const float* priorbox  = (const float*)d_in[2];
    const float* targets   = (const float*)d_in[3];
    float* out = (float*)d_out;

    char* ws = (char*)d_ws;
    unsigned long long* bestp = (unsigned long long*)(ws + OFF_BESTP);
    unsigned* h1c    = (unsigned*)(ws + OFF_H1C);
    float*    h1s    = (float*)(ws + OFF_H1S);
    unsigned* h1tot  = (unsigned*)(ws + OFF_H1TOT);
    float*    h1stot = (float*)(ws + OFF_H1STOT);
    int*      nposp  = (int*)(ws + OFF_NPOSP);
    float*    pcp    = (float*)(ws + OFF_PCP);
    float*    locp   = (float*)(ws + OFF_LOCP);
    unsigned* cidx   = (unsigned*)(ws + OFF_CIDX);
    unsigned* done   = (unsigned*)(ws + OFF_DONE);
    unsigned* bar    = (unsigned*)(ws + OFF_BAR);
    int*      resn   = (int*)(ws + OFF_RESN);
    int*      resk   = (int*)(ws + OFF_RESK);
    float*    resc   = (float*)(ws + OFF_RESC);
    float*    resl   = (float*)(ws + OFF_RESL);
    unsigned* cand   = (unsigned*)(ws + OFF_CAND);

    k_init<<<1, 128, 0, stream>>>(cidx, done, bar);
    k_all<<<dim3(NCHUNK, BB), 1024, 0, stream>>>(
        loc_preds, cls_preds, priorbox, targets, bestp, h1c, h1s, h1tot, h1stot,
        nposp, pcp, locp, cidx, done, bar, resn, resk, resc, resl, cand, out);
}

// Round 9
// 99.144 us; speedup vs baseline: 1.4634x; 1.4634x over previous
//
#include <hip/hip_runtime.h>

#define BB 16
#define PP 131072
#define GG 64
#define THRESH 0.35f
#define RMAX 0.086f          // max prior half-extent 0.085 + slop margin
#define NCH 32               // match/loss chunks per image
#define CPR 4096             // priors per match/loss chunk
#define NCC 16               // compact chunks per image
#define CPC 8192             // priors per compact chunk

// ---------------- workspace layout (bytes) ----------------
#define OFF_BESTG   0          // u64[BB][64]      8192
#define OFF_H1TOT   8192       // u32[BB][4096]    262144
#define OFF_H1STOT  270336     // f32[BB][4096]    262144
#define OFF_NPOSI   532480     // i32[BB]          64
#define OFF_PCI     532544     // f32[BB]          64
#define OFF_LOCI    532608     // f32[BB]          64
#define OFF_CIDX    532672     // u32[BB]          64
#define OFF_DONE    532736     // u32              64
#define OFF_SELI    532800     // i32[BB][4]       256  (sel1,kk1,np,k)
#define OFF_RESN    533056     // i32[BB]
#define OFF_RESK    533120     // i32[BB]
#define OFF_RESC    533184     // f32[BB]
#define OFF_RESL    533248     // f32[BB]
#define OFF_PU8     533312     // u8[BB*PP]        2097152
#define OFF_KEYS    2630464    // u32[BB*PP]       8388608
#define OFF_CAND    11019072   // u32[BB*PP]       8388608   (total ~19.4 MB)

// ---------------- init: zero accumulators (poison-proof) ----------------
__global__ __launch_bounds__(1024) void k_init(
    unsigned* __restrict__ bestg32, int* __restrict__ nposi, float* __restrict__ pci,
    float* __restrict__ loci, unsigned* __restrict__ cidx, unsigned* __restrict__ done)
{
    const int t = threadIdx.x;
    bestg32[t] = 0u; bestg32[t + 1024] = 0u;            // BB*64 u64 = 2048 u32
    if (t < BB) { nposi[t] = 0; pci[t] = 0.f; loci[t] = 0.f; cidx[t] = 0u; }
    if (t == BB) *done = 0u;
}

// ---------------- kernel 1: raster mask + match ----------------
// grid (NCH, BB) x 1024; 4 priors/thread strided by 1024. 2 blocks/CU (32 waves).
__global__ __launch_bounds__(1024, 8) void k_match(
    const float* __restrict__ priorbox, const float* __restrict__ targets,
    unsigned long long* __restrict__ bestg, unsigned char* __restrict__ pu8,
    unsigned* __restrict__ h1tot, float* __restrict__ h1stot)
{
    __shared__ unsigned msk[8192];                      // u64 mask per cell, interleaved
    __shared__ float4 gxy[GG];
    __shared__ unsigned long long sbest[GG];
    const int b = blockIdx.y, chunk = blockIdx.x, tid = threadIdx.x;

    // zero this block's slice of the global histograms (ready before k_loss)
    {
        const int zb = (b * NCH + chunk) * 128;
        if (tid < 128) h1tot[zb + tid] = 0u;
        else if (tid < 256) h1stot[zb + tid - 128] = 0.f;
    }
    for (int i = tid; i < 8192; i += 1024) msk[i] = 0u;
    if (tid < GG) {
        const float* t = targets + (size_t)(b * GG + tid) * 5;
        gxy[tid] = make_float4(t[1], t[0], t[3], t[2]); // gts = t[[1,0,3,2]]
        sbest[tid] = 0ull;
    }
    __syncthreads();

    // rasterize expanded gt boxes into the 64x64 cell bitmask
    {
        const int g = tid & 63, strip = tid >> 6;
        float4 a = gxy[g];
        int cx0 = max(0, (int)((a.x - RMAX) * 64.f));
        int cx1 = min(63, (int)ceilf((a.z + RMAX) * 64.f) - 1);
        int cy0 = max(0, (int)((a.y - RMAX) * 64.f));
        int cy1 = min(63, (int)ceilf((a.w + RMAX) * 64.f) - 1);
        unsigned bit = 1u << (g & 31);
        const int word = (g >> 5);
        for (int cy = cy0 + strip; cy <= cy1; cy += 16)
            for (int cx = cx0; cx <= cx1; cx++)
                atomicOr(&msk[2 * (cy * 64 + cx) + word], bit);
    }
    __syncthreads();

#pragma unroll
    for (int j = 0; j < 4; j++) {
        const int p = chunk * CPR + j * 1024 + tid;
        float4 pr = *reinterpret_cast<const float4*>(priorbox + (size_t)p * 4);
        float hx = 0.5f * pr.z, hy = 0.5f * pr.w;
        float px1 = pr.x - hx, py1 = pr.y - hy;
        float px2 = pr.x + hx, py2 = pr.y + hy;
        float par = (px2 - px1) * (py2 - py1);
        int cx = min(63, max(0, (int)(pr.x * 64.f)));
        int cy = min(63, max(0, (int)(pr.y * 64.f)));
        uint2 mm = *reinterpret_cast<uint2*>(&msk[2 * (cy * 64 + cx)]);
        unsigned long long m = ((unsigned long long)mm.y << 32) | mm.x;
        const unsigned long long notp = (unsigned long long)(~(unsigned)p);
        float bv = -1.f; int bg = 0;
        while (m) {
            // extract TWO set bits per iteration: two independent LDS reads in
            // flight halve the dependent-chain length (latency-bound loop).
            const int g0 = __ffsll(m) - 1; m &= m - 1;
            const bool has1 = (m != 0ull);
            const int g1 = has1 ? (__ffsll(m) - 1) : g0;
            if (has1) m &= m - 1;
            float4 a0 = gxy[g0];
            float4 a1 = gxy[g1];
            float w0 = fmaxf(fminf(a0.z, px2) - fmaxf(a0.x, px1), 0.f);
            float h0 = fmaxf(fminf(a0.w, py2) - fmaxf(a0.y, py1), 0.f);
            float w1 = fmaxf(fminf(a1.z, px2) - fmaxf(a1.x, px1), 0.f);
            float h1 = fmaxf(fminf(a1.w, py2) - fmaxf(a1.y, py1), 0.f);
            float ar0 = (a0.z - a0.x) * (a0.w - a0.y);   // recompute: kills LDS dep
            float ar1 = (a1.z - a1.x) * (a1.w - a1.y);
            float i0 = w0 * h0, i1 = w1 * h1;
            float v0 = i0 * __builtin_amdgcn_rcpf(ar0 + par - i0);
            float v1 = i1 * __builtin_amdgcn_rcpf(ar1 + par - i1);
            if (v0 > bv) { bv = v0; bg = g0; }           // g0<g1, iters ascending:
            if (has1 && v1 > bv) { bv = v1; bg = g1; }   // first-max tiebreak kept
            if (v0 > 0.f)
                atomicMax(&sbest[g0],
                          (((unsigned long long)__float_as_uint(v0)) << 32) | notp);
            if (has1 && v1 > 0.f)
                atomicMax(&sbest[g1],
                          (((unsigned long long)__float_as_uint(v1)) << 32) | notp);
        }
        pu8[(size_t)b * PP + p] = (unsigned char)(bg | ((bv >= THRESH) ? 0x80 : 0));
    }

    __syncthreads();
    if (tid < GG) {
        unsigned long long s = sbest[tid];
        if (s) atomicMax(&bestg[b * GG + tid], s);       // 32 adds/address
    }
}

// ---------------- kernel 2: loss + keys + global hist ----------------
// grid (NCH, BB) x 1024; 4 priors/thread strided by 1024.
__global__ __launch_bounds__(1024, 8) void k_loss(
    const float* __restrict__ loc_preds, const float* __restrict__ cls_preds,
    const float* __restrict__ priorbox, const float* __restrict__ targets,
    const unsigned long long* __restrict__ bestg, const unsigned char* __restrict__ pu8,
    unsigned* __restrict__ keys, unsigned* __restrict__ h1tot, float* __restrict__ h1stot,
    int* __restrict__ nposi, float* __restrict__ pci, float* __restrict__ loci)
{
    __shared__ unsigned hcnt[4096];
    __shared__ float hsum[4096];
    __shared__ float4 gxy[GG];
    __shared__ float glab[GG];
    __shared__ unsigned blist[GG];
    __shared__ int nb;
    __shared__ float sred[32];
    __shared__ int sredi[16];
    const int b = blockIdx.y, chunk = blockIdx.x, tid = threadIdx.x;
    const int lane = tid & 63, wid = tid >> 6;

    for (int i = tid; i < 4096; i += 1024) { hcnt[i] = 0u; hsum[i] = 0.f; }
    if (tid < GG) {
        const float* t = targets + (size_t)(b * GG + tid) * 5;
        gxy[tid] = make_float4(t[1], t[0], t[3], t[2]);
        glab[tid] = t[4];
    }
    __syncthreads();
    if (tid == 0) {
        int n = 0;
        for (int g = 0; g < GG; g++) {                   // ascending g: later-g wins
            unsigned long long m = bestg[b * GG + g];
            if (m) {
                unsigned p = ~((unsigned)(m & 0xFFFFFFFFull));
                if ((int)(p >> 12) == chunk)
                    blist[n++] = (((p & (CPR - 1)) << 6) | (unsigned)g);
            }
        }
        nb = n;
    }
    __syncthreads();

    const int nbl = nb;
    float locpart = 0.f, clspart = 0.f; int cnt = 0;
#pragma unroll
    for (int j = 0; j < 4; j++) {
        const int plocal = j * 1024 + tid;
        const size_t ip = (size_t)b * PP + chunk * CPR + plocal;
        const unsigned m8 = pu8[ip];
        int g = m8 & 63;
        bool pos = (m8 >> 7) != 0;
        for (int i = 0; i < nbl; i++) {
            unsigned e = blist[i];
            if ((int)(e >> 6) == plocal) { pos = true; g = (int)(e & 63u); }
        }
        const float2 cl = *reinterpret_cast<const float2*>(cls_preds + ip * 2);
        const float mx = fmaxf(cl.x, cl.y);
        const float lse = mx + log1pf(expf(fminf(cl.x, cl.y) - mx));
        unsigned key = 0u;
        if (pos && glab[g] > 0.f) {
            float gathered = (((int)glab[g]) == 0) ? cl.x : cl.y;
            clspart += lse - gathered;
            cnt++;
            const int p = chunk * CPR + plocal;
            float4 pr = *reinterpret_cast<const float4*>(priorbox + (size_t)p * 4);
            float4 gt = gxy[g];
            float gcx = ((gt.x + gt.z) * 0.5f - pr.x) / (0.1f * pr.z);
            float gcy = ((gt.y + gt.w) * 0.5f - pr.y) / (0.1f * pr.w);
            float gw = logf((gt.z - gt.x) / pr.z) / 0.2f;
            float gh = logf((gt.w - gt.y) / pr.w) / 0.2f;
            float4 lp = *reinterpret_cast<const float4*>(loc_preds + ip * 4);
            float d0 = lp.x - gcx, d1 = lp.y - gcy, d2 = lp.z - gw, d3 = lp.w - gh;
            float a0 = fabsf(d0), a1 = fabsf(d1), a2 = fabsf(d2), a3 = fabsf(d3);
            locpart += ((a0 < 1.f) ? 0.5f * d0 * d0 : a0 - 0.5f)
                     + ((a1 < 1.f) ? 0.5f * d1 * d1 : a1 - 0.5f)
                     + ((a2 < 1.f) ? 0.5f * d2 * d2 : a2 - 0.5f)
                     + ((a3 < 1.f) ? 0.5f * d3 * d3 : a3 - 0.5f);
        } else {
            float lc = lse - cl.x;                       // > 0 strictly for negs
            key = __float_as_uint(lc);
            atomicAdd(&hcnt[key >> 20], 1u);
            atomicAdd(&hsum[key >> 20], lc);
        }
        keys[ip] = key;
    }

    for (int o = 32; o; o >>= 1) {
        locpart += __shfl_xor(locpart, o);
        clspart += __shfl_xor(clspart, o);
        cnt     += __shfl_xor(cnt, o);
    }
    if (lane == 0) { sred[wid] = locpart; sred[16 + wid] = clspart; sredi[wid] = cnt; }
    __syncthreads();
    if (tid == 0) {
        float l = 0.f, c = 0.f; int n = 0;
        for (int i = 0; i < 16; i++) { l += sred[i]; c += sred[16 + i]; n += sredi[i]; }
        if (n)        atomicAdd(&nposi[b], n);           // 32 adds/address
        if (c != 0.f) atomicAdd(&pci[b], c);
        if (l != 0.f) atomicAdd(&loci[b], l);
    }
    __syncthreads();
    for (int i = tid; i < 4096; i += 1024) {             // ~400 nonzero bins/block
        unsigned cc = hcnt[i];
        if (cc) {
            atomicAdd(&h1tot[b * 4096 + i], cc);
            atomicAdd(&h1stot[b * 4096 + i], hsum[i]);
        }
    }
}

// ---------------- parallel descending k-th finder (1024-thread block) ----------------
template <int NBINS>
__device__ void find_kth_par(const unsigned* __restrict__ h, int k, int* sel, int* krem)
{
    constexpr int PER = NBINS / 1024;
    __shared__ unsigned wsum_[16];
    __shared__ int res_[2];
    const int tid = threadIdx.x, lane = tid & 63, wid = tid >> 6;
    __syncthreads();
    unsigned own[PER];
    unsigned s = 0;
#pragma unroll
    for (int i = 0; i < PER; i++) { own[i] = h[NBINS - 1 - (tid * PER + i)]; s += own[i]; }
    unsigned incl = s;
    for (int d = 1; d < 64; d <<= 1) {
        unsigned t = __shfl_up(incl, d);
        if (lane >= d) incl += t;
    }
    if (lane == 63) wsum_[wid] = incl;
    if (tid == 0) { res_[0] = -1; res_[1] = 0; }
    __syncthreads();
    unsigned woff = 0;
    for (int w = 0; w < 16; w++) woff += (w < wid) ? wsum_[w] : 0u;
    const unsigned texcl = woff + incl - s;
    if (k > 0 && texcl < (unsigned)k && texcl + s >= (unsigned)k) {
        unsigned run = texcl;
#pragma unroll
        for (int i = 0; i < PER; i++) {
            run += own[i];
            if (run >= (unsigned)k) {
                res_[0] = NBINS - 1 - (tid * PER + i);
                res_[1] = k - (int)(run - own[i]);
                break;
            }
        }
    }
    __syncthreads();
    *sel = res_[0]; *krem = res_[1];
}

__device__ float block_sum_f(float v)
{
    __shared__ float rs[16];
    const int tid = threadIdx.x;
    __syncthreads();
    for (int o = 32; o; o >>= 1) v += __shfl_xor(v, o);
    if ((tid & 63) == 0) rs[tid >> 6] = v;
    __syncthreads();
    float s = 0.f;
    for (int i = 0; i < 16; i++) s += rs[i];
    return s;
}

// ---------------- kernel 3: sel1 (redundant) + compact bucket-sel1 keys ----------------
// grid (NCC, BB) x 1024, 8 keys/thread; 1 returning atomic per block.
__global__ __launch_bounds__(1024) void k_compact(
    const unsigned* __restrict__ keys, const unsigned* __restrict__ h1tot,
    const int* __restrict__ nposi, unsigned* __restrict__ cand,
    unsigned* __restrict__ cidx, int* __restrict__ seli)
{
    __shared__ unsigned wcnt[16], wbase[16];
    __shared__ unsigned bbase;
    const int b = blockIdx.y, chunk = blockIdx.x, tid = threadIdx.x;
    const int lane = tid & 63, wid = tid >> 6;

    unsigned kv[8];
#pragma unroll
    for (int j = 0; j < 8; j++)
        kv[j] = keys[(size_t)b * PP + chunk * CPC + j * 1024 + tid];

    const int np = nposi[b];
    const int k = min(3 * np, PP - 1);
    int sel1, kk1;
    find_kth_par<4096>(h1tot + b * 4096, k, &sel1, &kk1);
    if (chunk == 0 && tid == 0) {
        seli[b * 4 + 0] = sel1; seli[b * 4 + 1] = kk1;
        seli[b * 4 + 2] = np;   seli[b * 4 + 3] = k;
    }
    const unsigned s1 = (unsigned)sel1;                  // -1 matches nothing

    unsigned long long mv[8];
    unsigned wn = 0;
#pragma unroll
    for (int j = 0; j < 8; j++) {
        mv[j] = __ballot((kv[j] >> 20) == s1);
        wn += (unsigned)__popcll(mv[j]);
    }
    if (lane == 0) wcnt[wid] = wn;
    __syncthreads();
    if (tid == 0) {
        unsigned run = 0;
        for (int w = 0; w < 16; w++) { wbase[w] = run; run += wcnt[w]; }
        bbase = run ? atomicAdd(&cidx[b], run) : 0u;
    }
    __syncthreads();
    unsigned run = bbase + wbase[wid];
    const unsigned long long lanemask = (1ull << lane) - 1ull;
#pragma unroll
    for (int j = 0; j < 8; j++) {
        if ((kv[j] >> 20) == s1)
            cand[(size_t)b * PP + run + (unsigned)__popcll(mv[j] & lanemask)] = kv[j];
        run += (unsigned)__popcll(mv[j]);
    }
}

// ---------------- kernel 4: exact top-k among candidates + final ----------------
__global__ __launch_bounds__(1024) void k_select(
    const unsigned* __restrict__ cand, const unsigned* __restrict__ cidx,
    const float* __restrict__ h1stot, const int* __restrict__ seli,
    const float* __restrict__ pci, const float* __restrict__ loci,
    int* __restrict__ resn, int* __restrict__ resk,
    float* __restrict__ resc, float* __restrict__ resl,
    unsigned* __restrict__ done, float* __restrict__ out)
{
    __shared__ unsigned ch[1024];
    __shared__ float cs[1024];
    __shared__ int lastflag;
    const int b = blockIdx.x, tid = threadIdx.x;
    const int sel1 = seli[b * 4 + 0], kk1 = seli[b * 4 + 1];
    const int np   = seli[b * 4 + 2], k   = seli[b * 4 + 3];
    const unsigned ncand = cidx[b];

    float nh = 0.f;
    for (int i = tid; i < 4096; i += 1024)
        if (i > sel1) nh += h1stot[b * 4096 + i];
    float negsum_high = block_sum_f(nh);

    __syncthreads();
    ch[tid] = 0u; cs[tid] = 0.f;
    __syncthreads();
    for (unsigned i = tid; i < ncand; i += 1024) {
        unsigned v = cand[(size_t)b * PP + i];
        unsigned bin = (v >> 10) & 1023u;
        atomicAdd(&ch[bin], 1u);
        atomicAdd(&cs[bin], __uint_as_float(v));
    }
    __syncthreads();
    int sel2, kk2;
    find_kth_par<1024>(ch, (sel1 < 0) ? 0 : kk1, &sel2, &kk2);
    float sumhi2 = block_sum_f((sel2 >= 0 && tid > sel2) ? cs[tid] : 0.f);

    __syncthreads();
    ch[tid] = 0u; cs[tid] = 0.f;
    __syncthreads();
    if (sel2 >= 0) {
        for (unsigned i = tid; i < ncand; i += 1024) {
            unsigned v = cand[(size_t)b * PP + i];
            if (((v >> 10) & 1023u) == (unsigned)sel2) {
                atomicAdd(&ch[v & 1023u], 1u);
                atomicAdd(&cs[v & 1023u], __uint_as_float(v));
            }
        }
    }
    __syncthreads();
    int sel3, needeq;
    find_kth_par<1024>(ch, (sel2 < 0) ? 0 : kk2, &sel3, &needeq);
    float sumhi3 = block_sum_f((sel3 >= 0 && tid > sel3) ? cs[tid] : 0.f);

    if (tid == 0) {
        float add = 0.f;
        if (sel3 >= 0 && needeq > 0) {
            unsigned Kstar = ((unsigned)sel1 << 20) | ((unsigned)sel2 << 10) | (unsigned)sel3;
            add = needeq * __uint_as_float(Kstar);
        }
        resn[b] = np;
        resk[b] = k;
        resc[b] = pci[b] + negsum_high + sumhi2 + sumhi3 + add;
        resl[b] = loci[b];
        __threadfence();
        unsigned old = atomicAdd(done, 1u);
        lastflag = (old == BB - 1) ? 1 : 0;
    }
    __syncthreads();
    if (!lastflag || tid != 0) return;

    __threadfence();
    volatile int* vrn = (volatile int*)resn;
    volatile int* vrk = (volatile int*)resk;
    volatile float* vrc = (volatile float*)resc;
    volatile float* vrl = (volatile float*)resl;
    int npt = 0; long long maskc = 0; float clsnum = 0.f, locnum = 0.f;
    for (int b2 = 0; b2 < BB; b2++) {
        npt += vrn[b2];
        maskc += (long long)vrn[b2] + vrk[b2];
        clsnum += vrc[b2];
        locnum += vrl[b2];
    }
    float denom_loc = (float)((4 * npt > 1) ? 4 * npt : 1);
    float denom_cls = (float)((maskc > 1) ? maskc : 1);
    float loss_loc = locnum / denom_loc;
    float loss_cls = clsnum / denom_cls;
    out[0] = (loss_cls + loss_loc) / (float)npt;
    out[1] = loss_loc;
    out[2] = loss_cls;
}

extern "C" void kernel_launch(void* const* d_in, const int* in_sizes, int n_in,
                              void* d_out, int out_size, void* d_ws, size_t ws_size,
                              hipStream_t stream)
{
    const float* loc_preds = (const float*)d_in[0];
    const float* cls_preds = (const float*)d_in[1];
    const float* priorbox  = (const float*)d_in[2];
    const float* targets   = (const float*)d_in[3];
    float* out = (float*)d_out;

    char* ws = (char*)d_ws;
    unsigned long long* bestg = (unsigned long long*)(ws + OFF_BESTG);
    unsigned* h1tot  = (unsigned*)(ws + OFF_H1TOT);
    float*    h1stot = (float*)(ws + OFF_H1STOT);
    int*      nposi  = (int*)(ws + OFF_NPOSI);
    float*    pci    = (float*)(ws + OFF_PCI);
    float*    loci   = (float*)(ws + OFF_LOCI);
    unsigned* cidx   = (unsigned*)(ws + OFF_CIDX);
    unsigned* done   = (unsigned*)(ws + OFF_DONE);
    int*      seli   = (int*)(ws + OFF_SELI);
    int*      resn   = (int*)(ws + OFF_RESN);
    int*      resk   = (int*)(ws + OFF_RESK);
    float*    resc   = (float*)(ws + OFF_RESC);
    float*    resl   = (float*)(ws + OFF_RESL);
    unsigned char* pu8 = (unsigned char*)(ws + OFF_PU8);
    unsigned* keys   = (unsigned*)(ws + OFF_KEYS);
    unsigned* cand   = (unsigned*)(ws + OFF_CAND);

    k_init<<<1, 1024, 0, stream>>>((unsigned*)bestg, nposi, pci, loci, cidx, done);
    k_match<<<dim3(NCH, BB), 1024, 0, stream>>>(priorbox, targets, bestg, pu8,
                                                h1tot, h1stot);
    k_loss<<<dim3(NCH, BB), 1024, 0, stream>>>(loc_preds, cls_preds, priorbox, targets,
                                               bestg, pu8, keys, h1tot, h1stot,
                                               nposi, pci, loci);
    k_compact<<<dim3(NCC, BB), 1024, 0, stream>>>(keys, h1tot, nposi, cand, cidx, seli);
    k_select<<<BB, 1024, 0, stream>>>(cand, cidx, h1stot, seli, pci, loci,
                                      resn, resk, resc, resl, done, out);
}